// Round 4
// baseline (261.046 us; speedup 1.0000x reference)
//
#include <hip/hip_runtime.h>
#include <hip/hip_bf16.h>
#include <hip/hip_fp16.h>

// GCN forward: emb-gather -> GCNConv(64->128) -> ReLU -> GCNConv(128->128) -> ReLU
//              -> global_max_pool -> Linear(128->10)
// N=100000, E=600000, VOCAB=5000, G=2000, C=10.
// fp16 intermediates (table T, h1, P) — error budget ~1e-3 << 3.5e-3 threshold.
// Aggregation kernels: quarter-wave (16 lanes x 8 features) per 4 consecutive nodes,
// unified contiguous CSR edge span with predicated accumulation -> max gather MLP.

typedef _Float16 h8 __attribute__((ext_vector_type(8)));
typedef float f32x4 __attribute__((ext_vector_type(4)));

__global__ __launch_bounds__(256) void k_deg(const int* __restrict__ dst, int* __restrict__ deg, int E) {
    int e = blockIdx.x * 256 + threadIdx.x;
    if (e < E) atomicAdd(&deg[dst[e]], 1);
}

// scan1 + dinv fused
__global__ __launch_bounds__(256) void k_scan1(const int* __restrict__ deg, int* __restrict__ exc,
                                               int* __restrict__ bsums, float* __restrict__ dinv, int N) {
    __shared__ int s[256];
    int i = blockIdx.x * 256 + threadIdx.x;
    int v = (i < N) ? deg[i] : 0;
    if (i < N) dinv[i] = rsqrtf((float)(v + 1));  // +1 self-loop
    s[threadIdx.x] = v;
    __syncthreads();
    for (int off = 1; off < 256; off <<= 1) {
        int t = (threadIdx.x >= (unsigned)off) ? s[threadIdx.x - off] : 0;
        __syncthreads();
        s[threadIdx.x] += t;
        __syncthreads();
    }
    if (i < N) exc[i] = s[threadIdx.x] - v;
    if (threadIdx.x == 255) bsums[blockIdx.x] = s[255];
}

__global__ __launch_bounds__(512) void k_scan2(int* __restrict__ bsums, int nb) {
    __shared__ int s[512];
    int i = threadIdx.x;
    int v = (i < nb) ? bsums[i] : 0;
    s[i] = v;
    __syncthreads();
    for (int off = 1; off < 512; off <<= 1) {
        int t = (i >= off) ? s[i - off] : 0;
        __syncthreads();
        s[i] += t;
        __syncthreads();
    }
    if (i < nb) bsums[i] = s[i] - v;
}

__global__ __launch_bounds__(256) void k_scan3(int* __restrict__ rowstart, int* __restrict__ cursor,
                                               const int* __restrict__ bsums, int N, int E) {
    int i = blockIdx.x * 256 + threadIdx.x;
    if (i < N) {
        int r = rowstart[i] + bsums[blockIdx.x];
        rowstart[i] = r;
        cursor[i] = r;
    }
    if (i == 0 && blockIdx.x == 0) rowstart[N] = E;
}

// CSR fill + per-edge record {x[src], dinv[src]}
__global__ __launch_bounds__(256) void k_fill(const int* __restrict__ src, const int* __restrict__ dst,
                                              const int* __restrict__ x, const float* __restrict__ dinv,
                                              int* __restrict__ cursor, int* __restrict__ cols,
                                              int2* __restrict__ edata, int E) {
    int e = blockIdx.x * 256 + threadIdx.x;
    if (e < E) {
        int d = dst[e];
        int s = src[e];
        int pos = atomicAdd(&cursor[d], 1);
        cols[pos] = s;
        edata[pos] = make_int2(x[s], __float_as_int(dinv[s]));
    }
}

// T[v] = (emb[v] @ W1) as fp16, (VOCAB x 128)
__global__ __launch_bounds__(256) void k_embW1(const float* __restrict__ emb, const float* __restrict__ W1,
                                               __half2* __restrict__ T, int VOCAB) {
    int t = blockIdx.x * 256 + threadIdx.x;
    if (t >= VOCAB * 32) return;
    int v = t >> 5, cq = t & 31;
    const float* er = emb + (size_t)v * 64;
    float4 acc = make_float4(0.f, 0.f, 0.f, 0.f);
#pragma unroll 8
    for (int k = 0; k < 64; ++k) {
        float e = er[k];
        float4 w = *(const float4*)&W1[k * 128 + cq * 4];
        acc.x += e * w.x; acc.y += e * w.y; acc.z += e * w.z; acc.w += e * w.w;
    }
    __half2* o = T + (size_t)v * 64 + cq * 2;
    o[0] = __floats2half2_rn(acc.x, acc.y);
    o[1] = __floats2half2_rn(acc.z, acc.w);
}

// W2T[c][k] = (fp16) W2[k][c]  (128x128)
__global__ __launch_bounds__(256) void k_w2t(const float* __restrict__ W2, _Float16* __restrict__ W2T) {
    int t = blockIdx.x * 256 + threadIdx.x;
    if (t >= 128 * 128) return;
    int c = t >> 7, k = t & 127;
    W2T[c * 128 + k] = (_Float16)W2[k * 128 + c];
}

// Layer-1: h1[i] = relu(di*(di*T[x_i] + sum_e dj*T[xj]) + b1), fp16 out.
// Quarter-wave per 4 consecutive nodes; unified edge span with predicated accumulate.
__global__ __launch_bounds__(256) void k_agg1(const h8* __restrict__ T8, const int* __restrict__ x,
                                              const float* __restrict__ dinv, const int* __restrict__ rs,
                                              const int2* __restrict__ edata, const float* __restrict__ bias,
                                              h8* __restrict__ h1, int N) {
    int lane16 = threadIdx.x & 15;
    int n0 = (blockIdx.x * 16 + (threadIdx.x >> 4)) * 4;
    if (n0 >= N) return;
    int c0 = rs[n0], c1 = rs[n0 + 1], c2 = rs[n0 + 2], c3 = rs[n0 + 3], c4 = rs[n0 + 4];
    float d0 = dinv[n0], d1 = dinv[n0 + 1], d2 = dinv[n0 + 2], d3 = dinv[n0 + 3];
    h8 s0 = T8[(size_t)x[n0] * 16 + lane16];
    h8 s1 = T8[(size_t)x[n0 + 1] * 16 + lane16];
    h8 s2 = T8[(size_t)x[n0 + 2] * 16 + lane16];
    h8 s3 = T8[(size_t)x[n0 + 3] * 16 + lane16];
    float a0[8], a1[8], a2[8], a3[8];
#pragma unroll
    for (int f = 0; f < 8; ++f) {
        a0[f] = d0 * (float)s0[f];
        a1[f] = d1 * (float)s1[f];
        a2[f] = d2 * (float)s2[f];
        a3[f] = d3 * (float)s3[f];
    }
    for (int e = c0; e < c4; e += 4) {
        int2 ed0 = edata[e];
        int2 ed1 = (e + 1 < c4) ? edata[e + 1] : ed0;
        int2 ed2 = (e + 2 < c4) ? edata[e + 2] : ed0;
        int2 ed3 = (e + 3 < c4) ? edata[e + 3] : ed0;
        h8 t0 = T8[(size_t)ed0.x * 16 + lane16];
        h8 t1 = T8[(size_t)ed1.x * 16 + lane16];
        h8 t2 = T8[(size_t)ed2.x * 16 + lane16];
        h8 t3 = T8[(size_t)ed3.x * 16 + lane16];
#pragma unroll
        for (int i = 0; i < 4; ++i) {
            int ei = e + i;
            int2 ed = (i == 0) ? ed0 : (i == 1) ? ed1 : (i == 2) ? ed2 : ed3;
            h8 tt = (i == 0) ? t0 : (i == 1) ? t1 : (i == 2) ? t2 : t3;
            float dj = __int_as_float(ed.y);
            float w0 = (ei < c1) ? dj : 0.f;
            float w1 = (ei >= c1 && ei < c2) ? dj : 0.f;
            float w2 = (ei >= c2 && ei < c3) ? dj : 0.f;
            float w3 = (ei >= c3 && ei < c4) ? dj : 0.f;
#pragma unroll
            for (int f = 0; f < 8; ++f) {
                float tf = (float)tt[f];
                a0[f] = fmaf(w0, tf, a0[f]);
                a1[f] = fmaf(w1, tf, a1[f]);
                a2[f] = fmaf(w2, tf, a2[f]);
                a3[f] = fmaf(w3, tf, a3[f]);
            }
        }
    }
    float4 bb0 = *(const float4*)&bias[lane16 * 8];
    float4 bb1 = *(const float4*)&bias[lane16 * 8 + 4];
    float bv[8] = {bb0.x, bb0.y, bb0.z, bb0.w, bb1.x, bb1.y, bb1.z, bb1.w};
    h8 o0, o1, o2, o3;
#pragma unroll
    for (int f = 0; f < 8; ++f) {
        o0[f] = (_Float16)fmaxf(fmaf(d0, a0[f], bv[f]), 0.f);
        o1[f] = (_Float16)fmaxf(fmaf(d1, a1[f], bv[f]), 0.f);
        o2[f] = (_Float16)fmaxf(fmaf(d2, a2[f], bv[f]), 0.f);
        o3[f] = (_Float16)fmaxf(fmaf(d3, a3[f], bv[f]), 0.f);
    }
    h1[(size_t)n0 * 16 + lane16] = o0;
    h1[(size_t)(n0 + 1) * 16 + lane16] = o1;
    h1[(size_t)(n0 + 2) * 16 + lane16] = o2;
    h1[(size_t)(n0 + 3) * 16 + lane16] = o3;
}

// P = dinv[i] * (h1 @ W2), fp16 out. MFMA 16x16x32_f16, wave = 16 rows x 128 cols. No LDS.
__global__ __launch_bounds__(256) void k_gemm(const _Float16* __restrict__ A, const _Float16* __restrict__ W2T,
                                              const float* __restrict__ dinv, _Float16* __restrict__ P, int N) {
    int lane = threadIdx.x & 63;
    int wid = threadIdx.x >> 6;
    int r = lane & 15, kg = lane >> 4;
    int row0 = blockIdx.x * 64 + wid * 16;
    int arow = row0 + r;
    if (arow >= N) arow = N - 1;
    const _Float16* ab = A + (size_t)arow * 128 + kg * 8;
    const _Float16* bb = W2T + (size_t)r * 128 + kg * 8;
    f32x4 acc[8];
#pragma unroll
    for (int ct = 0; ct < 8; ++ct) acc[ct] = (f32x4){0.f, 0.f, 0.f, 0.f};
#pragma unroll
    for (int kc = 0; kc < 4; ++kc) {
        h8 a = *(const h8*)(ab + kc * 32);
#pragma unroll
        for (int ct = 0; ct < 8; ++ct) {
            h8 b = *(const h8*)(bb + kc * 32 + ct * 2048);
            acc[ct] = __builtin_amdgcn_mfma_f32_16x16x32_f16(a, b, acc[ct], 0, 0, 0);
        }
    }
    float dv[4];
#pragma unroll
    for (int i = 0; i < 4; ++i) {
        int gr = row0 + 4 * kg + i;
        dv[i] = (gr < N) ? dinv[gr] : 0.f;
    }
#pragma unroll
    for (int ct = 0; ct < 8; ++ct) {
#pragma unroll
        for (int i = 0; i < 4; ++i) {
            int gr = row0 + 4 * kg + i;
            if (gr < N) P[(size_t)gr * 128 + ct * 16 + r] = (_Float16)(acc[ct][i] * dv[i]);
        }
    }
}

// Layer-2 + global_max_pool. Quarter-wave per 4 consecutive (batch-sorted) nodes,
// unified edge span, predicated accumulate, register run-max, boundary atomics, skip zeros.
__global__ __launch_bounds__(256) void k_agg2pool(const h8* __restrict__ P8, const int* __restrict__ batch,
                                                  const float* __restrict__ dinv, const int* __restrict__ rs,
                                                  const int* __restrict__ cols, const float* __restrict__ bias,
                                                  float* __restrict__ pool, int N) {
    int lane16 = threadIdx.x & 15;
    int n0 = (blockIdx.x * 16 + (threadIdx.x >> 4)) * 4;
    if (n0 >= N) return;
    int c0 = rs[n0], c1 = rs[n0 + 1], c2 = rs[n0 + 2], c3 = rs[n0 + 3], c4 = rs[n0 + 4];
    h8 s0 = P8[(size_t)n0 * 16 + lane16];
    h8 s1 = P8[(size_t)(n0 + 1) * 16 + lane16];
    h8 s2 = P8[(size_t)(n0 + 2) * 16 + lane16];
    h8 s3 = P8[(size_t)(n0 + 3) * 16 + lane16];
    float a0[8], a1[8], a2[8], a3[8];
#pragma unroll
    for (int f = 0; f < 8; ++f) {
        a0[f] = (float)s0[f];
        a1[f] = (float)s1[f];
        a2[f] = (float)s2[f];
        a3[f] = (float)s3[f];
    }
    for (int e = c0; e < c4; e += 4) {
        int j0 = cols[e];
        int j1 = (e + 1 < c4) ? cols[e + 1] : j0;
        int j2 = (e + 2 < c4) ? cols[e + 2] : j0;
        int j3 = (e + 3 < c4) ? cols[e + 3] : j0;
        h8 t0 = P8[(size_t)j0 * 16 + lane16];
        h8 t1 = P8[(size_t)j1 * 16 + lane16];
        h8 t2 = P8[(size_t)j2 * 16 + lane16];
        h8 t3 = P8[(size_t)j3 * 16 + lane16];
#pragma unroll
        for (int i = 0; i < 4; ++i) {
            int ei = e + i;
            h8 tt = (i == 0) ? t0 : (i == 1) ? t1 : (i == 2) ? t2 : t3;
            float w0 = (ei < c1) ? 1.f : 0.f;
            float w1 = (ei >= c1 && ei < c2) ? 1.f : 0.f;
            float w2 = (ei >= c2 && ei < c3) ? 1.f : 0.f;
            float w3 = (ei >= c3 && ei < c4) ? 1.f : 0.f;
#pragma unroll
            for (int f = 0; f < 8; ++f) {
                float tf = (float)tt[f];
                a0[f] = fmaf(w0, tf, a0[f]);
                a1[f] = fmaf(w1, tf, a1[f]);
                a2[f] = fmaf(w2, tf, a2[f]);
                a3[f] = fmaf(w3, tf, a3[f]);
            }
        }
    }
    float d0 = dinv[n0], d1 = dinv[n0 + 1], d2 = dinv[n0 + 2], d3 = dinv[n0 + 3];
    int g0 = batch[n0], g1 = batch[n0 + 1], g2 = batch[n0 + 2], g3 = batch[n0 + 3];
    float4 bb0 = *(const float4*)&bias[lane16 * 8];
    float4 bb1 = *(const float4*)&bias[lane16 * 8 + 4];
    float bv[8] = {bb0.x, bb0.y, bb0.z, bb0.w, bb1.x, bb1.y, bb1.z, bb1.w};
    float z0[8], z1[8], z2[8], z3[8];
#pragma unroll
    for (int f = 0; f < 8; ++f) {
        z0[f] = fmaxf(fmaf(d0, a0[f], bv[f]), 0.f);
        z1[f] = fmaxf(fmaf(d1, a1[f], bv[f]), 0.f);
        z2[f] = fmaxf(fmaf(d2, a2[f], bv[f]), 0.f);
        z3[f] = fmaxf(fmaf(d3, a3[f], bv[f]), 0.f);
    }
#define EMIT(g, m)                                                                      \
    {                                                                                   \
        float* pg = pool + (size_t)(g)*128 + lane16 * 8;                                \
        _Pragma("unroll") for (int f = 0; f < 8; ++f) {                                 \
            if (m[f] > 0.f) atomicMax((int*)(pg + f), __float_as_int(m[f]));            \
        }                                                                               \
    }
    float m[8];
#pragma unroll
    for (int f = 0; f < 8; ++f) m[f] = z0[f];
    int gcur = g0;
    if (g1 != gcur) {
        EMIT(gcur, m);
        gcur = g1;
#pragma unroll
        for (int f = 0; f < 8; ++f) m[f] = z1[f];
    } else {
#pragma unroll
        for (int f = 0; f < 8; ++f) m[f] = fmaxf(m[f], z1[f]);
    }
    if (g2 != gcur) {
        EMIT(gcur, m);
        gcur = g2;
#pragma unroll
        for (int f = 0; f < 8; ++f) m[f] = z2[f];
    } else {
#pragma unroll
        for (int f = 0; f < 8; ++f) m[f] = fmaxf(m[f], z2[f]);
    }
    if (g3 != gcur) {
        EMIT(gcur, m);
        gcur = g3;
#pragma unroll
        for (int f = 0; f < 8; ++f) m[f] = z3[f];
    } else {
#pragma unroll
        for (int f = 0; f < 8; ++f) m[f] = fmaxf(m[f], z3[f]);
    }
    EMIT(gcur, m);
#undef EMIT
}

// out[g][c] = blin[c] + sum_f pool[g][f] * Wlin[f][c]
__global__ __launch_bounds__(256) void k_final(const float* __restrict__ pool, const float* __restrict__ Wlin,
                                               const float* __restrict__ blin, float* __restrict__ out, int G) {
    int t = blockIdx.x * 256 + threadIdx.x;
    if (t >= G * 10) return;
    int g = t / 10, c = t % 10;
    float acc = blin[c];
    const float* pr = pool + (size_t)g * 128;
#pragma unroll 8
    for (int f = 0; f < 128; ++f) acc = fmaf(pr[f], Wlin[f * 10 + c], acc);
    out[t] = acc;
}

extern "C" void kernel_launch(void* const* d_in, const int* in_sizes, int n_in,
                              void* d_out, int out_size, void* d_ws, size_t ws_size,
                              hipStream_t stream) {
    const int* x = (const int*)d_in[0];
    const int* ei = (const int*)d_in[1];
    const int* batch = (const int*)d_in[2];
    const float* emb = (const float*)d_in[4];
    const float* W1 = (const float*)d_in[5];
    const float* b1 = (const float*)d_in[6];
    const float* W2 = (const float*)d_in[7];
    const float* b2 = (const float*)d_in[8];
    const float* Wlin = (const float*)d_in[9];
    const float* blin = (const float*)d_in[10];
    float* out = (float*)d_out;

    int N = in_sizes[0];
    int E = in_sizes[1] / 2;
    int VOCAB = in_sizes[4] / 64;
    int G = out_size / 10;
    const int* srcp = ei;
    const int* dstp = ei + E;

    char* p = (char*)d_ws;
    auto alloc = [&](size_t bytes) -> char* {
        char* r = p;
        p += (bytes + 255) & ~(size_t)255;
        return r;
    };
    int* deg = (int*)alloc((size_t)N * 4);
    int* cursor = (int*)alloc((size_t)N * 4);
    int* rowstart = (int*)alloc((size_t)(N + 1) * 4);
    int* bsums = (int*)alloc(512 * 4);
    float* dinv = (float*)alloc((size_t)N * 4);
    int* cols = (int*)alloc((size_t)E * 4);
    int2* edata = (int2*)alloc((size_t)E * 8);
    _Float16* T = (_Float16*)alloc((size_t)VOCAB * 128 * 2);
    _Float16* W2T = (_Float16*)alloc(128 * 128 * 2);
    _Float16* h1 = (_Float16*)alloc((size_t)N * 128 * 2);
    _Float16* P = (_Float16*)alloc((size_t)N * 128 * 2);
    float* pool = (float*)alloc((size_t)G * 128 * 4);

    hipMemsetAsync(deg, 0, (size_t)N * 4, stream);
    hipMemsetAsync(pool, 0, (size_t)G * 128 * 4, stream);

    int gE = (E + 255) / 256;
    int gN = (N + 255) / 256;  // 391 <= 512 (scan2 capacity)

    k_deg<<<gE, 256, 0, stream>>>(dstp, deg, E);
    k_scan1<<<gN, 256, 0, stream>>>(deg, rowstart, bsums, dinv, N);
    k_scan2<<<1, 512, 0, stream>>>(bsums, gN);
    k_scan3<<<gN, 256, 0, stream>>>(rowstart, cursor, bsums, N, E);
    k_fill<<<gE, 256, 0, stream>>>(srcp, dstp, x, dinv, cursor, cols, edata, E);
    k_embW1<<<(VOCAB * 32 + 255) / 256, 256, 0, stream>>>(emb, W1, (__half2*)T, VOCAB);
    k_w2t<<<64, 256, 0, stream>>>(W2, W2T);
    // quarter-wave kernels: 16 quarter-waves/block, 4 nodes each -> 64 nodes/block
    int gQ = (N + 63) / 64;
    k_agg1<<<gQ, 256, 0, stream>>>((const h8*)T, x, dinv, rowstart, edata, b1, (h8*)h1, N);
    k_gemm<<<(N + 63) / 64, 256, 0, stream>>>(h1, W2T, dinv, P, N);
    k_agg2pool<<<gQ, 256, 0, stream>>>((const h8*)P, batch, dinv, rowstart, cols, b2, pool, N);
    k_final<<<(G * 10 + 255) / 256, 256, 0, stream>>>(pool, Wlin, blin, out, G);
}

// Round 5
// 222.645 us; speedup vs baseline: 1.1725x; 1.1725x over previous
//
#include <hip/hip_runtime.h>
#include <hip/hip_bf16.h>
#include <hip/hip_fp16.h>

// GCN forward: emb-gather -> GCNConv(64->128) -> ReLU -> GCNConv(128->128) -> ReLU
//              -> global_max_pool -> Linear(128->10)
// N=100000, E=600000, VOCAB=5000, G=2000, C=10.
// fp16 intermediates (T, h1, P). Aggregations: half-wave (32 lanes x 4 fp16 = 256B/row)
// per 4 consecutive nodes, per-node edge loop with 8-wide clamped unroll (8 rows in flight).

typedef _Float16 h4v __attribute__((ext_vector_type(4)));
typedef _Float16 h8 __attribute__((ext_vector_type(8)));
typedef float f32x4 __attribute__((ext_vector_type(4)));

__global__ __launch_bounds__(256) void k_deg(const int* __restrict__ dst, int* __restrict__ deg, int E) {
    int e = blockIdx.x * 256 + threadIdx.x;
    if (e < E) atomicAdd(&deg[dst[e]], 1);
}

// scan1 + dinv fused
__global__ __launch_bounds__(256) void k_scan1(const int* __restrict__ deg, int* __restrict__ exc,
                                               int* __restrict__ bsums, float* __restrict__ dinv, int N) {
    __shared__ int s[256];
    int i = blockIdx.x * 256 + threadIdx.x;
    int v = (i < N) ? deg[i] : 0;
    if (i < N) dinv[i] = rsqrtf((float)(v + 1));  // +1 self-loop
    s[threadIdx.x] = v;
    __syncthreads();
    for (int off = 1; off < 256; off <<= 1) {
        int t = (threadIdx.x >= (unsigned)off) ? s[threadIdx.x - off] : 0;
        __syncthreads();
        s[threadIdx.x] += t;
        __syncthreads();
    }
    if (i < N) exc[i] = s[threadIdx.x] - v;
    if (threadIdx.x == 255) bsums[blockIdx.x] = s[255];
}

__global__ __launch_bounds__(512) void k_scan2(int* __restrict__ bsums, int nb) {
    __shared__ int s[512];
    int i = threadIdx.x;
    int v = (i < nb) ? bsums[i] : 0;
    s[i] = v;
    __syncthreads();
    for (int off = 1; off < 512; off <<= 1) {
        int t = (i >= off) ? s[i - off] : 0;
        __syncthreads();
        s[i] += t;
        __syncthreads();
    }
    if (i < nb) bsums[i] = s[i] - v;
}

__global__ __launch_bounds__(256) void k_scan3(int* __restrict__ rowstart, int* __restrict__ cursor,
                                               const int* __restrict__ bsums, int N, int E) {
    int i = blockIdx.x * 256 + threadIdx.x;
    if (i < N) {
        int r = rowstart[i] + bsums[blockIdx.x];
        rowstart[i] = r;
        cursor[i] = r;
    }
    if (i == 0 && blockIdx.x == 0) rowstart[N] = E;
}

// CSR fill + per-edge record {x[src], dinv[src]}
__global__ __launch_bounds__(256) void k_fill(const int* __restrict__ src, const int* __restrict__ dst,
                                              const int* __restrict__ x, const float* __restrict__ dinv,
                                              int* __restrict__ cursor, int* __restrict__ cols,
                                              int2* __restrict__ edata, int E) {
    int e = blockIdx.x * 256 + threadIdx.x;
    if (e < E) {
        int d = dst[e];
        int s = src[e];
        int pos = atomicAdd(&cursor[d], 1);
        cols[pos] = s;
        edata[pos] = make_int2(x[s], __float_as_int(dinv[s]));
    }
}

// Fused prep: blocks [0, nEmb) compute T[v] = fp16(emb[v] @ W1); blocks [nEmb, nEmb+64) do W2T.
__global__ __launch_bounds__(256) void k_prep(const float* __restrict__ emb, const float* __restrict__ W1,
                                              __half2* __restrict__ T, const float* __restrict__ W2,
                                              _Float16* __restrict__ W2T, int VOCAB, int nEmb) {
    int bid = blockIdx.x;
    if (bid < nEmb) {
        int t = bid * 256 + threadIdx.x;
        if (t >= VOCAB * 32) return;
        int v = t >> 5, cq = t & 31;
        const float* er = emb + (size_t)v * 64;
        float4 acc = make_float4(0.f, 0.f, 0.f, 0.f);
#pragma unroll 8
        for (int k = 0; k < 64; ++k) {
            float e = er[k];
            float4 w = *(const float4*)&W1[k * 128 + cq * 4];
            acc.x += e * w.x; acc.y += e * w.y; acc.z += e * w.z; acc.w += e * w.w;
        }
        __half2* o = T + (size_t)v * 64 + cq * 2;
        o[0] = __floats2half2_rn(acc.x, acc.y);
        o[1] = __floats2half2_rn(acc.z, acc.w);
    } else {
        int t = (bid - nEmb) * 256 + threadIdx.x;
        if (t >= 128 * 128) return;
        int c = t >> 7, k = t & 127;
        W2T[c * 128 + k] = (_Float16)W2[k * 128 + c];
    }
}

// Layer-1: h1[i] = relu(di*(di*T[x_i] + sum_e dj*T[xj]) + b1), fp16 out.
// Half-wave per 4 consecutive nodes; per-node edge loop, 8-wide clamped unroll.
__global__ __launch_bounds__(256) void k_agg1(const h4v* __restrict__ T4, const int* __restrict__ x,
                                              const float* __restrict__ dinv, const int* __restrict__ rs,
                                              const int2* __restrict__ edata, const float4* __restrict__ bias4,
                                              h4v* __restrict__ h1, int N) {
    int lane = threadIdx.x & 31;
    int n0 = (blockIdx.x * 8 + (threadIdx.x >> 5)) * 4;
    if (n0 >= N) return;
    if (n0 + 4 > N) n0 = N - 4;  // N%4==0 normally; clamp is value-safe (rewrites same data)
    int c[5];
#pragma unroll
    for (int k = 0; k < 5; ++k) c[k] = rs[n0 + k];
    float4 b = bias4[lane];
#pragma unroll
    for (int k = 0; k < 4; ++k) {
        int node = n0 + k;
        float di = dinv[node];
        h4v s = T4[(size_t)x[node] * 32 + lane];
        float a0 = di * (float)s[0], a1 = di * (float)s[1];
        float a2 = di * (float)s[2], a3 = di * (float)s[3];
        int e1 = c[k + 1];
        for (int e = c[k]; e < e1; e += 8) {
            h4v t[8];
            float w[8];
#pragma unroll
            for (int i = 0; i < 8; ++i) {
                int ei = e + i;
                int ec = (ei < e1) ? ei : e1 - 1;
                int2 ed = edata[ec];
                t[i] = T4[(size_t)ed.x * 32 + lane];
                w[i] = (ei < e1) ? __int_as_float(ed.y) : 0.f;
            }
#pragma unroll
            for (int i = 0; i < 8; ++i) {
                a0 = fmaf(w[i], (float)t[i][0], a0);
                a1 = fmaf(w[i], (float)t[i][1], a1);
                a2 = fmaf(w[i], (float)t[i][2], a2);
                a3 = fmaf(w[i], (float)t[i][3], a3);
            }
        }
        h4v o;
        o[0] = (_Float16)fmaxf(fmaf(di, a0, b.x), 0.f);
        o[1] = (_Float16)fmaxf(fmaf(di, a1, b.y), 0.f);
        o[2] = (_Float16)fmaxf(fmaf(di, a2, b.z), 0.f);
        o[3] = (_Float16)fmaxf(fmaf(di, a3, b.w), 0.f);
        h1[(size_t)node * 32 + lane] = o;
    }
}

// P = dinv[i] * (h1 @ W2), fp16 out. MFMA 16x16x32_f16, wave = 16 rows x 128 cols. No LDS.
__global__ __launch_bounds__(256) void k_gemm(const _Float16* __restrict__ A, const _Float16* __restrict__ W2T,
                                              const float* __restrict__ dinv, _Float16* __restrict__ P, int N) {
    int lane = threadIdx.x & 63;
    int wid = threadIdx.x >> 6;
    int r = lane & 15, kg = lane >> 4;
    int row0 = blockIdx.x * 64 + wid * 16;
    int arow = row0 + r;
    if (arow >= N) arow = N - 1;
    const _Float16* ab = A + (size_t)arow * 128 + kg * 8;
    const _Float16* bb = W2T + (size_t)r * 128 + kg * 8;
    f32x4 acc[8];
#pragma unroll
    for (int ct = 0; ct < 8; ++ct) acc[ct] = (f32x4){0.f, 0.f, 0.f, 0.f};
#pragma unroll
    for (int kc = 0; kc < 4; ++kc) {
        h8 a = *(const h8*)(ab + kc * 32);
#pragma unroll
        for (int ct = 0; ct < 8; ++ct) {
            h8 b = *(const h8*)(bb + kc * 32 + ct * 2048);
            acc[ct] = __builtin_amdgcn_mfma_f32_16x16x32_f16(a, b, acc[ct], 0, 0, 0);
        }
    }
    float dv[4];
#pragma unroll
    for (int i = 0; i < 4; ++i) {
        int gr = row0 + 4 * kg + i;
        dv[i] = (gr < N) ? dinv[gr] : 0.f;
    }
#pragma unroll
    for (int ct = 0; ct < 8; ++ct) {
#pragma unroll
        for (int i = 0; i < 4; ++i) {
            int gr = row0 + 4 * kg + i;
            if (gr < N) P[(size_t)gr * 128 + ct * 16 + r] = (_Float16)(acc[ct][i] * dv[i]);
        }
    }
}

// Layer-2 + global_max_pool. Half-wave per 4 consecutive (batch-sorted) nodes;
// per-node edge loop with 8-wide clamped unroll; register run-max; boundary atomics; skip zeros.
__global__ __launch_bounds__(256) void k_agg2pool(const h4v* __restrict__ P4, const int* __restrict__ batch,
                                                  const float* __restrict__ dinv, const int* __restrict__ rs,
                                                  const int* __restrict__ cols, const float4* __restrict__ bias4,
                                                  float* __restrict__ pool, int N) {
    int lane = threadIdx.x & 31;
    int n0 = (blockIdx.x * 8 + (threadIdx.x >> 5)) * 4;
    if (n0 >= N) return;
    if (n0 + 4 > N) n0 = N - 4;  // duplicates are idempotent for max-pool
    int c[5];
#pragma unroll
    for (int k = 0; k < 5; ++k) c[k] = rs[n0 + k];
    float4 b = bias4[lane];
    float m0 = 0.f, m1 = 0.f, m2 = 0.f, m3 = 0.f;
    int gcur = -1;
#define EMIT()                                                                       \
    {                                                                                \
        float* pg = pool + (size_t)gcur * 128 + lane * 4;                            \
        if (m0 > 0.f) atomicMax((int*)pg, __float_as_int(m0));                       \
        if (m1 > 0.f) atomicMax((int*)(pg + 1), __float_as_int(m1));                 \
        if (m2 > 0.f) atomicMax((int*)(pg + 2), __float_as_int(m2));                 \
        if (m3 > 0.f) atomicMax((int*)(pg + 3), __float_as_int(m3));                 \
    }
#pragma unroll
    for (int k = 0; k < 4; ++k) {
        int node = n0 + k;
        int g = batch[node];
        if (g != gcur) {
            if (gcur >= 0) EMIT();
            gcur = g;
            m0 = m1 = m2 = m3 = 0.f;
        }
        h4v s = P4[(size_t)node * 32 + lane];
        float a0 = (float)s[0], a1 = (float)s[1], a2 = (float)s[2], a3 = (float)s[3];
        int e1 = c[k + 1];
        for (int e = c[k]; e < e1; e += 8) {
            h4v t[8];
            float w[8];
#pragma unroll
            for (int i = 0; i < 8; ++i) {
                int ei = e + i;
                int ec = (ei < e1) ? ei : e1 - 1;
                t[i] = P4[(size_t)cols[ec] * 32 + lane];
                w[i] = (ei < e1) ? 1.f : 0.f;
            }
#pragma unroll
            for (int i = 0; i < 8; ++i) {
                a0 = fmaf(w[i], (float)t[i][0], a0);
                a1 = fmaf(w[i], (float)t[i][1], a1);
                a2 = fmaf(w[i], (float)t[i][2], a2);
                a3 = fmaf(w[i], (float)t[i][3], a3);
            }
        }
        float di = dinv[node];
        m0 = fmaxf(m0, fmaxf(fmaf(di, a0, b.x), 0.f));
        m1 = fmaxf(m1, fmaxf(fmaf(di, a1, b.y), 0.f));
        m2 = fmaxf(m2, fmaxf(fmaf(di, a2, b.z), 0.f));
        m3 = fmaxf(m3, fmaxf(fmaf(di, a3, b.w), 0.f));
    }
    if (gcur >= 0) EMIT();
#undef EMIT
}

// out[g][c] = blin[c] + sum_f pool[g][f] * Wlin[f][c]
__global__ __launch_bounds__(256) void k_final(const float* __restrict__ pool, const float* __restrict__ Wlin,
                                               const float* __restrict__ blin, float* __restrict__ out, int G) {
    int t = blockIdx.x * 256 + threadIdx.x;
    if (t >= G * 10) return;
    int g = t / 10, c = t % 10;
    float acc = blin[c];
    const float* pr = pool + (size_t)g * 128;
#pragma unroll 8
    for (int f = 0; f < 128; ++f) acc = fmaf(pr[f], Wlin[f * 10 + c], acc);
    out[t] = acc;
}

extern "C" void kernel_launch(void* const* d_in, const int* in_sizes, int n_in,
                              void* d_out, int out_size, void* d_ws, size_t ws_size,
                              hipStream_t stream) {
    const int* x = (const int*)d_in[0];
    const int* ei = (const int*)d_in[1];
    const int* batch = (const int*)d_in[2];
    const float* emb = (const float*)d_in[4];
    const float* W1 = (const float*)d_in[5];
    const float* b1 = (const float*)d_in[6];
    const float* W2 = (const float*)d_in[7];
    const float* b2 = (const float*)d_in[8];
    const float* Wlin = (const float*)d_in[9];
    const float* blin = (const float*)d_in[10];
    float* out = (float*)d_out;

    int N = in_sizes[0];
    int E = in_sizes[1] / 2;
    int VOCAB = in_sizes[4] / 64;
    int G = out_size / 10;
    const int* srcp = ei;
    const int* dstp = ei + E;

    char* p = (char*)d_ws;
    auto alloc = [&](size_t bytes) -> char* {
        char* r = p;
        p += (bytes + 255) & ~(size_t)255;
        return r;
    };
    int* deg = (int*)alloc((size_t)N * 4);
    int* cursor = (int*)alloc((size_t)N * 4);
    int* rowstart = (int*)alloc((size_t)(N + 1) * 4);
    int* bsums = (int*)alloc(512 * 4);
    float* dinv = (float*)alloc((size_t)N * 4);
    int* cols = (int*)alloc((size_t)E * 4);
    int2* edata = (int2*)alloc((size_t)E * 8);
    _Float16* T = (_Float16*)alloc((size_t)VOCAB * 128 * 2);
    _Float16* W2T = (_Float16*)alloc(128 * 128 * 2);
    _Float16* h1 = (_Float16*)alloc((size_t)N * 128 * 2);
    _Float16* P = (_Float16*)alloc((size_t)N * 128 * 2);
    float* pool = (float*)alloc((size_t)G * 128 * 4);

    hipMemsetAsync(deg, 0, (size_t)N * 4, stream);
    hipMemsetAsync(pool, 0, (size_t)G * 128 * 4, stream);

    int gE = (E + 255) / 256;
    int gN = (N + 255) / 256;  // 391 <= 512 (scan2 capacity)

    k_deg<<<gE, 256, 0, stream>>>(dstp, deg, E);
    k_scan1<<<gN, 256, 0, stream>>>(deg, rowstart, bsums, dinv, N);
    k_scan2<<<1, 512, 0, stream>>>(bsums, gN);
    k_scan3<<<gN, 256, 0, stream>>>(rowstart, cursor, bsums, N, E);
    k_fill<<<gE, 256, 0, stream>>>(srcp, dstp, x, dinv, cursor, cols, edata, E);
    int nEmb = (VOCAB * 32 + 255) / 256;
    k_prep<<<nEmb + 64, 256, 0, stream>>>(emb, W1, (__half2*)T, W2, W2T, VOCAB, nEmb);
    // half-wave kernels: 8 half-waves/block, 4 nodes each -> 32 nodes/block
    int gHW = (N + 31) / 32;
    k_agg1<<<gHW, 256, 0, stream>>>((const h4v*)T, x, dinv, rowstart, edata, (const float4*)b1,
                                    (h4v*)h1, N);
    k_gemm<<<(N + 63) / 64, 256, 0, stream>>>(h1, W2T, dinv, P, N);
    k_agg2pool<<<gHW, 256, 0, stream>>>((const h4v*)P, batch, dinv, rowstart, cols,
                                        (const float4*)b2, pool, N);
    k_final<<<(G * 10 + 255) / 256, 256, 0, stream>>>(pool, Wlin, blin, out, G);
}

// Round 6
// 209.096 us; speedup vs baseline: 1.2484x; 1.0648x over previous
//
#include <hip/hip_runtime.h>
#include <hip/hip_bf16.h>
#include <hip/hip_fp16.h>

// GCN forward: emb-gather -> GCNConv(64->128) -> ReLU -> GCNConv(128->128) -> ReLU
//              -> global_max_pool -> Linear(128->10)
// N=100000, E=600000, VOCAB=5000, G=2000, C=10.
// fp16 intermediates (T, h1, P). Aggregations: half-wave (32 lanes x 8B) per 2 consecutive
// nodes, dual 8-deep clamped gather batches issued before FMAs (18 rows in flight).
// agg2pool: 512-thr blocks (32 sorted nodes), per-node max -> LDS slots -> 1 global emit
// per (block, graph, feature).

typedef _Float16 h4v __attribute__((ext_vector_type(4)));
typedef _Float16 h8 __attribute__((ext_vector_type(8)));
typedef float f32x4 __attribute__((ext_vector_type(4)));

// Fused: blocks [0,gE) degree-count; [gE, gE+nEmb) T = fp16(emb@W1); rest W2T transpose.
__global__ __launch_bounds__(256) void k_degprep(const int* __restrict__ dst, int* __restrict__ deg, int E,
                                                 const float* __restrict__ emb, const float* __restrict__ W1,
                                                 __half2* __restrict__ T, const float* __restrict__ W2,
                                                 _Float16* __restrict__ W2T, int VOCAB, int gE, int nEmb) {
    int bid = blockIdx.x;
    if (bid < gE) {
        int e = bid * 256 + threadIdx.x;
        if (e < E) atomicAdd(&deg[dst[e]], 1);
    } else if (bid < gE + nEmb) {
        int t = (bid - gE) * 256 + threadIdx.x;
        if (t >= VOCAB * 32) return;
        int v = t >> 5, cq = t & 31;
        const float* er = emb + (size_t)v * 64;
        float4 acc = make_float4(0.f, 0.f, 0.f, 0.f);
#pragma unroll 8
        for (int k = 0; k < 64; ++k) {
            float e = er[k];
            float4 w = *(const float4*)&W1[k * 128 + cq * 4];
            acc.x += e * w.x; acc.y += e * w.y; acc.z += e * w.z; acc.w += e * w.w;
        }
        __half2* o = T + (size_t)v * 64 + cq * 2;
        o[0] = __floats2half2_rn(acc.x, acc.y);
        o[1] = __floats2half2_rn(acc.z, acc.w);
    } else {
        int t = (bid - gE - nEmb) * 256 + threadIdx.x;
        if (t >= 128 * 128) return;
        int c = t >> 7, k = t & 127;
        W2T[c * 128 + k] = (_Float16)W2[k * 128 + c];
    }
}

// scan1 + dinv fused
__global__ __launch_bounds__(256) void k_scan1(const int* __restrict__ deg, int* __restrict__ exc,
                                               int* __restrict__ bsums, float* __restrict__ dinv, int N) {
    __shared__ int s[256];
    int i = blockIdx.x * 256 + threadIdx.x;
    int v = (i < N) ? deg[i] : 0;
    if (i < N) dinv[i] = rsqrtf((float)(v + 1));  // +1 self-loop
    s[threadIdx.x] = v;
    __syncthreads();
    for (int off = 1; off < 256; off <<= 1) {
        int t = (threadIdx.x >= (unsigned)off) ? s[threadIdx.x - off] : 0;
        __syncthreads();
        s[threadIdx.x] += t;
        __syncthreads();
    }
    if (i < N) exc[i] = s[threadIdx.x] - v;
    if (threadIdx.x == 255) bsums[blockIdx.x] = s[255];
}

__global__ __launch_bounds__(512) void k_scan2(int* __restrict__ bsums, int nb) {
    __shared__ int s[512];
    int i = threadIdx.x;
    int v = (i < nb) ? bsums[i] : 0;
    s[i] = v;
    __syncthreads();
    for (int off = 1; off < 512; off <<= 1) {
        int t = (i >= off) ? s[i - off] : 0;
        __syncthreads();
        s[i] += t;
        __syncthreads();
    }
    if (i < nb) bsums[i] = s[i] - v;
}

__global__ __launch_bounds__(256) void k_scan3(int* __restrict__ rowstart, int* __restrict__ cursor,
                                               const int* __restrict__ bsums, int N, int E) {
    int i = blockIdx.x * 256 + threadIdx.x;
    if (i < N) {
        int r = rowstart[i] + bsums[blockIdx.x];
        rowstart[i] = r;
        cursor[i] = r;
    }
    if (i == 0 && blockIdx.x == 0) rowstart[N] = E;
}

// CSR fill: one 16B record per edge {x[src], dinv[src] bits, src, 0}
__global__ __launch_bounds__(256) void k_fill(const int* __restrict__ src, const int* __restrict__ dst,
                                              const int* __restrict__ x, const float* __restrict__ dinv,
                                              int* __restrict__ cursor, int4* __restrict__ rec, int E) {
    int e = blockIdx.x * 256 + threadIdx.x;
    if (e < E) {
        int d = dst[e];
        int s = src[e];
        int pos = atomicAdd(&cursor[d], 1);
        rec[pos] = make_int4(x[s], __float_as_int(dinv[s]), s, 0);
    }
}

// Layer-1: h1[i] = relu(di*(di*T[x_i] + sum_e dj*T[xj]) + b1), fp16 out.
// Half-wave per 2 nodes; both nodes' 8-deep clamped batches + selfs issued before FMAs.
__global__ __launch_bounds__(256) void k_agg1(const h4v* __restrict__ T4, const int* __restrict__ x,
                                              const float* __restrict__ dinv, const int* __restrict__ rs,
                                              const int4* __restrict__ rec, const float4* __restrict__ bias4,
                                              h4v* __restrict__ h1, int N) {
    int lane = threadIdx.x & 31;
    int n0 = (blockIdx.x * 8 + (threadIdx.x >> 5)) * 2;
    if (n0 >= N) return;
    int nB = (n0 + 1 < N) ? n0 + 1 : n0;
    int cA0 = rs[n0], cA1 = rs[n0 + 1];
    int cB0 = rs[nB], cB1 = rs[nB + 1];
    bool hasA = cA0 < cA1, hasB = cB0 < cB1;
    h4v tA[8], tB[8];
    float wA[8], wB[8];
    if (hasA) {
#pragma unroll
        for (int i = 0; i < 8; ++i) {
            int ei = cA0 + i;
            int ec = (ei < cA1) ? ei : cA1 - 1;
            int4 r = rec[ec];
            tA[i] = T4[(size_t)r.x * 32 + lane];
            wA[i] = (ei < cA1) ? __int_as_float(r.y) : 0.f;
        }
    }
    if (hasB) {
#pragma unroll
        for (int i = 0; i < 8; ++i) {
            int ei = cB0 + i;
            int ec = (ei < cB1) ? ei : cB1 - 1;
            int4 r = rec[ec];
            tB[i] = T4[(size_t)r.x * 32 + lane];
            wB[i] = (ei < cB1) ? __int_as_float(r.y) : 0.f;
        }
    }
    float dA = dinv[n0], dB = dinv[nB];
    h4v sA = T4[(size_t)x[n0] * 32 + lane];
    h4v sB = T4[(size_t)x[nB] * 32 + lane];
    float aA[4], aB[4];
#pragma unroll
    for (int f = 0; f < 4; ++f) {
        aA[f] = dA * (float)sA[f];
        aB[f] = dB * (float)sB[f];
    }
    if (hasA) {
#pragma unroll
        for (int i = 0; i < 8; ++i)
#pragma unroll
            for (int f = 0; f < 4; ++f) aA[f] = fmaf(wA[i], (float)tA[i][f], aA[f]);
    }
    if (hasB) {
#pragma unroll
        for (int i = 0; i < 8; ++i)
#pragma unroll
            for (int f = 0; f < 4; ++f) aB[f] = fmaf(wB[i], (float)tB[i][f], aB[f]);
    }
    for (int e = cA0 + 8; e < cA1; e += 8) {
#pragma unroll
        for (int i = 0; i < 8; ++i) {
            int ei = e + i;
            int ec = (ei < cA1) ? ei : cA1 - 1;
            int4 r = rec[ec];
            tA[i] = T4[(size_t)r.x * 32 + lane];
            wA[i] = (ei < cA1) ? __int_as_float(r.y) : 0.f;
        }
#pragma unroll
        for (int i = 0; i < 8; ++i)
#pragma unroll
            for (int f = 0; f < 4; ++f) aA[f] = fmaf(wA[i], (float)tA[i][f], aA[f]);
    }
    for (int e = cB0 + 8; e < cB1; e += 8) {
#pragma unroll
        for (int i = 0; i < 8; ++i) {
            int ei = e + i;
            int ec = (ei < cB1) ? ei : cB1 - 1;
            int4 r = rec[ec];
            tB[i] = T4[(size_t)r.x * 32 + lane];
            wB[i] = (ei < cB1) ? __int_as_float(r.y) : 0.f;
        }
#pragma unroll
        for (int i = 0; i < 8; ++i)
#pragma unroll
            for (int f = 0; f < 4; ++f) aB[f] = fmaf(wB[i], (float)tB[i][f], aB[f]);
    }
    float4 b = bias4[lane];
    float bv[4] = {b.x, b.y, b.z, b.w};
    h4v oA, oB;
#pragma unroll
    for (int f = 0; f < 4; ++f) {
        oA[f] = (_Float16)fmaxf(fmaf(dA, aA[f], bv[f]), 0.f);
        oB[f] = (_Float16)fmaxf(fmaf(dB, aB[f], bv[f]), 0.f);
    }
    h1[(size_t)n0 * 32 + lane] = oA;
    h1[(size_t)nB * 32 + lane] = oB;
}

// P = dinv[i] * (h1 @ W2), fp16 out. MFMA 16x16x32_f16, wave = 16 rows x 128 cols. No LDS.
__global__ __launch_bounds__(256) void k_gemm(const _Float16* __restrict__ A, const _Float16* __restrict__ W2T,
                                              const float* __restrict__ dinv, _Float16* __restrict__ P, int N) {
    int lane = threadIdx.x & 63;
    int wid = threadIdx.x >> 6;
    int r = lane & 15, kg = lane >> 4;
    int row0 = blockIdx.x * 64 + wid * 16;
    int arow = row0 + r;
    if (arow >= N) arow = N - 1;
    const _Float16* ab = A + (size_t)arow * 128 + kg * 8;
    const _Float16* bb = W2T + (size_t)r * 128 + kg * 8;
    f32x4 acc[8];
#pragma unroll
    for (int ct = 0; ct < 8; ++ct) acc[ct] = (f32x4){0.f, 0.f, 0.f, 0.f};
#pragma unroll
    for (int kc = 0; kc < 4; ++kc) {
        h8 a = *(const h8*)(ab + kc * 32);
#pragma unroll
        for (int ct = 0; ct < 8; ++ct) {
            h8 b = *(const h8*)(bb + kc * 32 + ct * 2048);
            acc[ct] = __builtin_amdgcn_mfma_f32_16x16x32_f16(a, b, acc[ct], 0, 0, 0);
        }
    }
    float dv[4];
#pragma unroll
    for (int i = 0; i < 4; ++i) {
        int gr = row0 + 4 * kg + i;
        dv[i] = (gr < N) ? dinv[gr] : 0.f;
    }
#pragma unroll
    for (int ct = 0; ct < 8; ++ct) {
#pragma unroll
        for (int i = 0; i < 4; ++i) {
            int gr = row0 + 4 * kg + i;
            if (gr < N) P[(size_t)gr * 128 + ct * 16 + r] = (_Float16)(acc[ct][i] * dv[i]);
        }
    }
}

// Layer-2 + global_max_pool. 512-thr block = 16 half-waves x 2 nodes = 32 sorted nodes.
// Per-node z -> per-half-wave max -> LDS graph slots (atomicMax) -> one global emit per
// (block, graph, feature). Slot overflow (>4 graphs/block) falls back to direct atomics.
__global__ __launch_bounds__(512) void k_agg2pool(const h4v* __restrict__ P4, const int* __restrict__ batch,
                                                  const float* __restrict__ dinv, const int* __restrict__ rs,
                                                  const int4* __restrict__ rec, const float4* __restrict__ bias4,
                                                  float* __restrict__ pool, int N, int G) {
    __shared__ int lpool[4][128];
    int tid = threadIdx.x;
    lpool[tid >> 7][tid & 127] = 0;
    __syncthreads();
    int lane = tid & 31;
    int blk_n0 = blockIdx.x * 32;
    int gfirst = batch[(blk_n0 < N) ? blk_n0 : (N - 1)];
    int n0 = blk_n0 + (tid >> 5) * 2;
    if (n0 < N) {
        int nB = (n0 + 1 < N) ? n0 + 1 : n0;
        int cA0 = rs[n0], cA1 = rs[n0 + 1];
        int cB0 = rs[nB], cB1 = rs[nB + 1];
        bool hasA = cA0 < cA1, hasB = cB0 < cB1;
        h4v tA[8], tB[8];
        float wA[8], wB[8];
        if (hasA) {
#pragma unroll
            for (int i = 0; i < 8; ++i) {
                int ei = cA0 + i;
                int ec = (ei < cA1) ? ei : cA1 - 1;
                tA[i] = P4[(size_t)rec[ec].z * 32 + lane];
                wA[i] = (ei < cA1) ? 1.f : 0.f;
            }
        }
        if (hasB) {
#pragma unroll
            for (int i = 0; i < 8; ++i) {
                int ei = cB0 + i;
                int ec = (ei < cB1) ? ei : cB1 - 1;
                tB[i] = P4[(size_t)rec[ec].z * 32 + lane];
                wB[i] = (ei < cB1) ? 1.f : 0.f;
            }
        }
        h4v sA = P4[(size_t)n0 * 32 + lane];
        h4v sB = P4[(size_t)nB * 32 + lane];
        float aA[4], aB[4];
#pragma unroll
        for (int f = 0; f < 4; ++f) {
            aA[f] = (float)sA[f];
            aB[f] = (float)sB[f];
        }
        if (hasA) {
#pragma unroll
            for (int i = 0; i < 8; ++i)
#pragma unroll
                for (int f = 0; f < 4; ++f) aA[f] = fmaf(wA[i], (float)tA[i][f], aA[f]);
        }
        if (hasB) {
#pragma unroll
            for (int i = 0; i < 8; ++i)
#pragma unroll
                for (int f = 0; f < 4; ++f) aB[f] = fmaf(wB[i], (float)tB[i][f], aB[f]);
        }
        for (int e = cA0 + 8; e < cA1; e += 8) {
#pragma unroll
            for (int i = 0; i < 8; ++i) {
                int ei = e + i;
                int ec = (ei < cA1) ? ei : cA1 - 1;
                tA[i] = P4[(size_t)rec[ec].z * 32 + lane];
                wA[i] = (ei < cA1) ? 1.f : 0.f;
            }
#pragma unroll
            for (int i = 0; i < 8; ++i)
#pragma unroll
                for (int f = 0; f < 4; ++f) aA[f] = fmaf(wA[i], (float)tA[i][f], aA[f]);
        }
        for (int e = cB0 + 8; e < cB1; e += 8) {
#pragma unroll
            for (int i = 0; i < 8; ++i) {
                int ei = e + i;
                int ec = (ei < cB1) ? ei : cB1 - 1;
                tB[i] = P4[(size_t)rec[ec].z * 32 + lane];
                wB[i] = (ei < cB1) ? 1.f : 0.f;
            }
#pragma unroll
            for (int i = 0; i < 8; ++i)
#pragma unroll
                for (int f = 0; f < 4; ++f) aB[f] = fmaf(wB[i], (float)tB[i][f], aB[f]);
        }
        float dA = dinv[n0], dB = dinv[nB];
        int gA = batch[n0], gB = batch[nB];
        float4 b = bias4[lane];
        float bv[4] = {b.x, b.y, b.z, b.w};
        float zA[4], zB[4];
#pragma unroll
        for (int f = 0; f < 4; ++f) {
            zA[f] = fmaxf(fmaf(dA, aA[f], bv[f]), 0.f);
            zB[f] = fmaxf(fmaf(dB, aB[f], bv[f]), 0.f);
        }
        auto emit = [&](int g, const float* m) {
            int slot = g - gfirst;
            if (slot < 4) {
#pragma unroll
                for (int f = 0; f < 4; ++f)
                    if (m[f] > 0.f) atomicMax(&lpool[slot][lane * 4 + f], __float_as_int(m[f]));
            } else {
                float* pg = pool + (size_t)g * 128 + lane * 4;
#pragma unroll
                for (int f = 0; f < 4; ++f)
                    if (m[f] > 0.f) atomicMax((int*)(pg + f), __float_as_int(m[f]));
            }
        };
        if (gA == gB) {
            float m[4];
#pragma unroll
            for (int f = 0; f < 4; ++f) m[f] = fmaxf(zA[f], zB[f]);
            emit(gA, m);
        } else {
            emit(gA, zA);
            emit(gB, zB);
        }
    }
    __syncthreads();
    int s = tid >> 7, f = tid & 127;
    int v = lpool[s][f];
    if (v > 0) atomicMax((int*)&pool[(size_t)(gfirst + s) * 128 + f], v);
}

// out[g][c] = blin[c] + sum_f pool[g][f] * Wlin[f][c]
__global__ __launch_bounds__(256) void k_final(const float* __restrict__ pool, const float* __restrict__ Wlin,
                                               const float* __restrict__ blin, float* __restrict__ out, int G) {
    int t = blockIdx.x * 256 + threadIdx.x;
    if (t >= G * 10) return;
    int g = t / 10, c = t % 10;
    float acc = blin[c];
    const float* pr = pool + (size_t)g * 128;
#pragma unroll 8
    for (int f = 0; f < 128; ++f) acc = fmaf(pr[f], Wlin[f * 10 + c], acc);
    out[t] = acc;
}

extern "C" void kernel_launch(void* const* d_in, const int* in_sizes, int n_in,
                              void* d_out, int out_size, void* d_ws, size_t ws_size,
                              hipStream_t stream) {
    const int* x = (const int*)d_in[0];
    const int* ei = (const int*)d_in[1];
    const int* batch = (const int*)d_in[2];
    const float* emb = (const float*)d_in[4];
    const float* W1 = (const float*)d_in[5];
    const float* b1 = (const float*)d_in[6];
    const float* W2 = (const float*)d_in[7];
    const float* b2 = (const float*)d_in[8];
    const float* Wlin = (const float*)d_in[9];
    const float* blin = (const float*)d_in[10];
    float* out = (float*)d_out;

    int N = in_sizes[0];
    int E = in_sizes[1] / 2;
    int VOCAB = in_sizes[4] / 64;
    int G = out_size / 10;
    const int* srcp = ei;
    const int* dstp = ei + E;

    char* p = (char*)d_ws;
    auto alloc = [&](size_t bytes) -> char* {
        char* r = p;
        p += (bytes + 255) & ~(size_t)255;
        return r;
    };
    int* deg = (int*)alloc((size_t)N * 4);
    int* cursor = (int*)alloc((size_t)N * 4);
    int* rowstart = (int*)alloc((size_t)(N + 1) * 4);
    int* bsums = (int*)alloc(512 * 4);
    float* dinv = (float*)alloc((size_t)N * 4);
    int4* rec = (int4*)alloc((size_t)E * 16);
    _Float16* T = (_Float16*)alloc((size_t)VOCAB * 128 * 2);
    _Float16* W2T = (_Float16*)alloc(128 * 128 * 2);
    _Float16* h1 = (_Float16*)alloc((size_t)N * 128 * 2);
    _Float16* P = (_Float16*)alloc((size_t)N * 128 * 2);
    float* pool = (float*)alloc((size_t)G * 128 * 4);

    hipMemsetAsync(deg, 0, (size_t)N * 4, stream);
    hipMemsetAsync(pool, 0, (size_t)G * 128 * 4, stream);

    int gE = (E + 255) / 256;
    int gN = (N + 255) / 256;  // 391 <= 512 (scan2 capacity)
    int nEmb = (VOCAB * 32 + 255) / 256;

    k_degprep<<<gE + nEmb + 64, 256, 0, stream>>>(dstp, deg, E, emb, W1, (__half2*)T, W2, W2T,
                                                  VOCAB, gE, nEmb);
    k_scan1<<<gN, 256, 0, stream>>>(deg, rowstart, bsums, dinv, N);
    k_scan2<<<1, 512, 0, stream>>>(bsums, gN);
    k_scan3<<<gN, 256, 0, stream>>>(rowstart, cursor, bsums, N, E);
    k_fill<<<gE, 256, 0, stream>>>(srcp, dstp, x, dinv, cursor, rec, E);
    // agg1: 256-thr block = 8 half-waves x 2 nodes = 16 nodes
    k_agg1<<<(N + 15) / 16, 256, 0, stream>>>((const h4v*)T, x, dinv, rowstart, rec,
                                              (const float4*)b1, (h4v*)h1, N);
    k_gemm<<<(N + 63) / 64, 256, 0, stream>>>(h1, W2T, dinv, P, N);
    // agg2pool: 512-thr block = 16 half-waves x 2 nodes = 32 nodes
    k_agg2pool<<<(N + 31) / 32, 512, 0, stream>>>((const h4v*)P, batch, dinv, rowstart, rec,
                                                  (const float4*)b2, pool, N, G);
    k_final<<<(G * 10 + 255) / 256, 256, 0, stream>>>(pool, Wlin, blin, out, G);
}